// Round 7
// baseline (818.171 us; speedup 1.0000x reference)
//
#include <hip/hip_runtime.h>
#include <hip/hip_bf16.h>

// ---------- helpers ----------
__device__ __forceinline__ float b2f(unsigned short u) {
    return __uint_as_float(((unsigned)u) << 16);
}
__device__ __forceinline__ unsigned short f2b(float f) {
    __hip_bfloat16 h = __float2bfloat16(f);
    return *reinterpret_cast<unsigned short*>(&h);
}
// cheap round-to-nearest-even bf16 (no NaN inputs in this pipeline)
__device__ __forceinline__ unsigned short f2b_rne(float f) {
    unsigned u = __float_as_uint(f);
    return (unsigned short)((u + 0x7fffu + ((u >> 16) & 1u)) >> 16);
}
__device__ __forceinline__ float sigm(float v) {
    return 1.f / (1.f + __expf(-v));
}
// tanh-approx GELU (max abs dev from exact ~1e-3; post-W2 contribution <1e-3)
__device__ __forceinline__ float gelu_t(float x) {
    float y = 0.7978845608f * (x + 0.044715f * x * x * x);
    float e = __expf(2.f * y);
    float th = 1.f - 2.f / (e + 1.f);
    return 0.5f * x * (1.f + th);
}

typedef __attribute__((ext_vector_type(8))) short s8v;   // 8 bf16 (4 VGPRs)
typedef __attribute__((ext_vector_type(4))) float f4v;   // 4 fp32 acc

#define MFMA_BF16 __builtin_amdgcn_mfma_f32_16x16x32_bf16

// ---------- 15-feature map (per input coordinate) ----------
__device__ __forceinline__ void make_feats(const unsigned short* __restrict__ qpts,
                                           int r, float* __restrict__ f) {
    unsigned pq = *(const unsigned*)(qpts + (size_t)r * 2);
    float x0 = b2f((unsigned short)(pq & 0xffff));
    float x1 = b2f((unsigned short)(pq >> 16));
    const float PI = 3.14159265358979323846f;
    float a0 = x0 - 1.5f, a1 = x1 - 1.5f, c0 = x0 - 4.5f, c1 = x1 - 4.5f;
    f[0] = x0;        f[1] = x1;
    f[2] = x0 * x0;   f[3] = x1 * x1;
    f[4] = a0 * a0;   f[5] = a1 * a1;
    f[6] = c0 * c0;   f[7] = c1 * c1;
    f[8] = sigm(x0);  f[9] = sigm(x1);
    f[10] = sigm(a0); f[11] = sigm(a1);
    f[12] = sigm(c0); f[13] = sigm(c1);
    f[14] = a0;       f[15] = a1;
    f[16] = c0;       f[17] = c1;
    f[18] = __sinf(PI * x0);          f[19] = __sinf(PI * x1);
    f[20] = __cosf(PI * x0);          f[21] = __cosf(PI * x1);
    f[22] = __sinf(PI * 0.25f * x0);  f[23] = __sinf(PI * 0.25f * x1);
    f[24] = __cosf(PI * 0.25f * x0);  f[25] = __cosf(PI * 0.25f * x1);
    f[26] = __sinf(PI * 0.5f * x0);   f[27] = __sinf(PI * 0.5f * x1);
    f[28] = __cosf(PI * 0.5f * x0);   f[29] = __cosf(PI * 0.5f * x1);
}

// ---------- canonicalize all inputs to bf16 (embedded dtype detection) ----------
struct ConvArgs {
    const void* p[22];
    int off[23];
};

__global__ __launch_bounds__(256) void convert_kernel(
    ConvArgs a, const unsigned short* __restrict__ pe_w_raw,
    int* __restrict__ flag, unsigned short* __restrict__ canon, int total)
{
    __shared__ int cnt;
    if (threadIdx.x == 0) cnt = 0;
    __syncthreads();
    float v = b2f(pe_w_raw[threadIdx.x * 2]);
    if (!(fabsf(v) < 1.0f)) atomicAdd(&cnt, 1);
    __syncthreads();
    int isf32 = (cnt >= 16) ? 1 : 0;
    if (blockIdx.x == 0 && threadIdx.x == 0) *flag = isf32;

    int g = blockIdx.x * 256 + threadIdx.x;
    if (g >= total) return;
    int s = 0;
    #pragma unroll
    for (int i = 1; i < 23; i++) s += (g >= a.off[i]) ? 1 : 0;
    int local = g - a.off[s];
    unsigned short r;
    if (isf32) r = f2b(((const float*)a.p[s])[local]);
    else       r = ((const unsigned short*)a.p[s])[local];
    canon[g] = r;
}

// ---------- boundary positional encoding (M rows, fp32 out) ----------
__global__ __launch_bounds__(256) void encode_kernel(
    const unsigned short* __restrict__ pts,
    const unsigned short* __restrict__ w,
    const unsigned short* __restrict__ b,
    float* __restrict__ out)
{
    __shared__ __align__(16) float wsm[30 * 128];
    __shared__ float bs[128];
    int t = threadIdx.x;
    for (int i = t; i < 30 * 128; i += 256) wsm[i] = b2f(w[i]);
    if (t < 128) bs[t] = b2f(b[t]);
    __syncthreads();

    int r = blockIdx.x * 8 + (t >> 5);
    int j = t & 31;
    float f[30];
    make_feats(pts, r, f);
    float s0 = bs[j * 4 + 0], s1 = bs[j * 4 + 1], s2 = bs[j * 4 + 2], s3 = bs[j * 4 + 3];
    #pragma unroll
    for (int ff = 0; ff < 30; ff++) {
        float4 wv = *(const float4*)&wsm[ff * 128 + j * 4];
        float fv = f[ff];
        s0 += fv * wv.x; s1 += fv * wv.y; s2 += fv * wv.z; s3 += fv * wv.w;
    }
    *(float4*)&out[(size_t)r * 128 + j * 4] =
        make_float4(__sinf(s0), __sinf(s1), __sinf(s2), __sinf(s3));
}

// ---------- boundary k/v heads (+ zeroing of kv/ks accumulators) ----------
__global__ __launch_bounds__(256) void khvh_kernel(
    const float* __restrict__ benc,
    const unsigned short* __restrict__ Wk, const unsigned short* __restrict__ bk,
    const unsigned short* __restrict__ Wv, const unsigned short* __restrict__ bv,
    float* __restrict__ kh, float* __restrict__ vh, float* __restrict__ kvz)
{
    int g = blockIdx.x * 256 + threadIdx.x;
    if (g < 12672) kvz[g] = 0.f;   // kvs(12288) + kss(384), contiguous
    int lh = g >> 17;
    int rem = g & 131071;
    int m = rem >> 5;
    int dd = rem & 31;
    const unsigned short* wk = Wk + lh * 4096 + dd;
    const unsigned short* wv = Wv + lh * 4096 + dd;
    const float* br = benc + (size_t)m * 128;
    float ka = 0.f, va = 0.f;
    #pragma unroll 8
    for (int c = 0; c < 128; c++) {
        float bb = br[c];
        ka += bb * b2f(wk[c * 32]);
        va += bb * b2f(wv[c * 32]);
    }
    ka += b2f(bk[lh * 32 + dd]); ka = ka * ka;
    va += b2f(bv[lh * 32 + dd]);
    kh[g] = ka; vh[g] = va;
}

// ---------- reduce over boundary points: kvsum[lh][d][e], ksum[lh][d] ----------
__global__ __launch_bounds__(1024) void kvred_kernel(
    const float* __restrict__ kh, const float* __restrict__ vh,
    float* __restrict__ kvsum, float* __restrict__ ksum)
{
    __shared__ float khs[1024];
    __shared__ float vhs[1024];
    int t = threadIdx.x;
    int lh = blockIdx.x >> 3;
    int part = blockIdx.x & 7;
    int dd = t >> 5, ee = t & 31;
    float kva = 0.f, ksa = 0.f;
    for (int ch = 0; ch < 16; ch++) {
        int base = lh * 131072 + (part * 16 + ch) * 1024;
        khs[t] = kh[base + t];
        vhs[t] = vh[base + t];
        __syncthreads();
        #pragma unroll
        for (int i = 0; i < 32; i++) {
            float kk = khs[i * 32 + dd];
            kva += kk * vhs[i * 32 + ee];
            ksa += kk;
        }
        __syncthreads();
    }
    atomicAdd(&kvsum[lh * 1024 + dd * 32 + ee], kva);
    if (ee == 0) atomicAdd(&ksum[lh * 32 + dd], ksa);
}

// ---------- prep: transposes + Wa fold + Ks matrix, one kernel ----------
__global__ __launch_bounds__(256) void prep_kernel(
    const unsigned short* __restrict__ Wq, const unsigned short* __restrict__ W1,
    const unsigned short* __restrict__ W2, const unsigned short* __restrict__ pw1,
    const float* __restrict__ kvs, const float* __restrict__ kss,
    const unsigned short* __restrict__ Wo,
    unsigned short* __restrict__ wqT, unsigned short* __restrict__ w1T,
    unsigned short* __restrict__ w2T, unsigned short* __restrict__ pw1T,
    unsigned short* __restrict__ waT, unsigned short* __restrict__ ksT)
{
    int g = blockIdx.x * 256 + threadIdx.x;
    if (g < 49152) {
        int l = g >> 14, r = g & 16383, n = r >> 7, k = r & 127;
        wqT[g] = Wq[((l * 4 + (n >> 5)) * 128 + k) * 32 + (n & 31)];  // head-interleaved cols
    } else if (g < 98304) {
        int q = g - 49152; int l = q >> 14, r = q & 16383, n = r >> 7, k = r & 127;
        w1T[q] = W1[(l * 128 + k) * 128 + n];
    } else if (g < 147456) {
        int q = g - 98304; int l = q >> 14, r = q & 16383, n = r >> 7, k = r & 127;
        w2T[q] = W2[(l * 128 + k) * 128 + n];
    } else if (g < 155648) {
        int q = g - 147456; int n = q >> 7, k = q & 127;
        pw1T[q] = pw1[k * 64 + n];
    } else if (g < 204800) {
        int q = g - 155648; int l = q >> 14, r = q & 16383, n = r >> 7, k = r & 127;
        int hk = k >> 5, dk = k & 31;
        const float* kvp = kvs + (l * 4 + hk) * 1024 + dk * 32;
        const unsigned short* wop = Wo + (size_t)(l * 128 + hk * 32) * 128 + n;
        float s = 0.f;
        #pragma unroll 8
        for (int j = 0; j < 32; j++) s += kvp[j] * b2f(wop[j * 128]);
        waT[q] = f2b(s);
    } else if (g < 210944) {
        int q = g - 204800; int l = q >> 11, r = q & 2047, n = r >> 7, k = r & 127;
        unsigned short v = 0;
        if (n < 4 && (k >> 5) == n) v = f2b(kss[(l * 4 + n) * 32 + (k & 31)]);
        ksT[q] = v;
    }
}

// ---------- the fused mega kernel: encode + 3 layers + projector ----------
// 128 rows/block, 4 waves; wave w owns rows [w*32, w*32+32) = 2 MFMA row-tiles.
// Weights read as B-fragments DIRECTLY FROM GLOBAL (L2-hot), no barriers in
// the layer loop (activations wave-private; same-wave LDS ops are in order).
// ALL mm loops are textual macros so every array index is a compile-time
// constant after unrolling -> hres[2][4][8] stays in VGPRs (round-5's lambda
// version demoted it to scratch: 860 MB of HBM spill traffic). NOTE: inside
// macro arguments, #pragma is illegal -> use _Pragma("unroll").
#define LDA 136   // LDS row stride in ushorts (272B = 17*16B)

// mm over 8 col-tiles of a 128x128 [n][k] weight matrix; B-frags from global
// with prefetch-1. EPI sees: tc, x0 (rows r0c..+3), x1 (rows r0c+16..+19).
#define RUN_MM(AF, W, ...) do {                                               \
    const unsigned short* _base = (W) + l16 * 128 + qd * 8;                   \
    s8v _c0 = *(const s8v*)(_base);                                           \
    s8v _c1 = *(const s8v*)(_base + 32);                                      \
    s8v _c2 = *(const s8v*)(_base + 64);                                      \
    s8v _c3 = *(const s8v*)(_base + 96);                                      \
    _Pragma("unroll")                                                         \
    for (int tc = 0; tc < 8; tc++) {                                          \
        s8v _n0, _n1, _n2, _n3;                                               \
        if (tc < 7) {                                                         \
            const unsigned short* _bp = _base + (tc + 1) * 2048;              \
            _n0 = *(const s8v*)(_bp);      _n1 = *(const s8v*)(_bp + 32);     \
            _n2 = *(const s8v*)(_bp + 64); _n3 = *(const s8v*)(_bp + 96);     \
        }                                                                     \
        f4v x0 = {0.f, 0.f, 0.f, 0.f}, x1 = {0.f, 0.f, 0.f, 0.f};             \
        x0 = MFMA_BF16(AF[0][0], _c0, x0, 0, 0, 0);                           \
        x1 = MFMA_BF16(AF[1][0], _c0, x1, 0, 0, 0);                           \
        x0 = MFMA_BF16(AF[0][1], _c1, x0, 0, 0, 0);                           \
        x1 = MFMA_BF16(AF[1][1], _c1, x1, 0, 0, 0);                           \
        x0 = MFMA_BF16(AF[0][2], _c2, x0, 0, 0, 0);                           \
        x1 = MFMA_BF16(AF[1][2], _c2, x1, 0, 0, 0);                           \
        x0 = MFMA_BF16(AF[0][3], _c3, x0, 0, 0, 0);                           \
        x1 = MFMA_BF16(AF[1][3], _c3, x1, 0, 0, 0);                           \
        { __VA_ARGS__ }                                                       \
        if (tc < 7) { _c0 = _n0; _c1 = _n1; _c2 = _n2; _c3 = _n3; }           \
    }                                                                         \
} while (0)

// load A-fragments (2 row-tiles) for this wave's rows from sA
#define LOAD_AF(AF) do {                                                      \
    _Pragma("unroll")                                                         \
    for (int _t = 0; _t < 2; _t++)                                            \
        _Pragma("unroll")                                                     \
        for (int _k = 0; _k < 4; _k++)                                        \
            AF[_t][_k] = *(const s8v*)&sA[(rA0 + _t * 16) * LDA + _k * 32 + qd * 8]; \
} while (0)

__global__ __launch_bounds__(256, 2) void mega_kernel(
    const unsigned short* __restrict__ qpts,
    const unsigned short* __restrict__ pe_w,
    const unsigned short* __restrict__ pe_b,
    const unsigned short* __restrict__ wqT,
    const unsigned short* __restrict__ waT,
    const unsigned short* __restrict__ ksT,
    const unsigned short* __restrict__ w1T,
    const unsigned short* __restrict__ w2T,
    const unsigned short* __restrict__ bq,
    const unsigned short* __restrict__ bo,
    const unsigned short* __restrict__ b1,
    const unsigned short* __restrict__ b2,
    const unsigned short* __restrict__ pw1T,
    const unsigned short* __restrict__ pb1,
    const unsigned short* __restrict__ pw2,
    const unsigned short* __restrict__ pb2,
    void* __restrict__ outv, const int* __restrict__ flag)
{
    __shared__ __align__(16) unsigned short sA[128 * LDA];   // 34816 B activations
    __shared__ __align__(16) float pws[30 * 128];            // 15360 B
    __shared__ __align__(16) unsigned short sKsAll[3 * 16 * LDA]; // 13056 B
    __shared__ float biasAll[12 * 128];                      // 6144 B [l][{q,o,1,2}][c]
    __shared__ float pebs[128];
    __shared__ float pb1s[64];
    __shared__ float w2s[192];
    __shared__ float pb2s[3];
    __shared__ float dens[128 * 4];                          // 2048 B

    int t = threadIdx.x;
    int wvi = t >> 6, ln = t & 63, qd = ln >> 4, l16 = ln & 15;
    int row0 = blockIdx.x * 128;
    int rA0 = wvi * 32 + l16;        // A-frag row, tile 0 (tile 1: +16)
    int r0c = wvi * 32 + qd * 4;     // C base row, tile 0 (tile 1: +16)

    // ===== one-time staging =====
    for (int i = t; i < 3840; i += 256) pws[i] = b2f(pe_w[i]);
    #pragma unroll
    for (int ll = 0; ll < 3; ll++)
        *(int4*)&sKsAll[(ll * 16 + (t >> 4)) * LDA + (t & 15) * 8] =
            ((const int4*)(ksT + ll * 2048))[t];
    for (int i = t; i < 1536; i += 256) {
        int l = i >> 9, rem = i & 511, which = rem >> 7, c = rem & 127;
        const unsigned short* bsrc = (which == 0) ? bq : (which == 1) ? bo
                                   : (which == 2) ? b1 : b2;
        biasAll[i] = b2f(bsrc[l * 128 + c]);
    }
    if (t < 128) pebs[t] = b2f(pe_b[t]);
    if (t < 64)  pb1s[t] = b2f(pb1[t]);
    if (t < 192) w2s[t] = b2f(pw2[t]);
    if (t < 3)   pb2s[t] = b2f(pb2[t]);
    __syncthreads();     // barrier #1 (the only one before the tail)

    // ===== encode: h = sin(feats @ pe_w + pe_b), vectorized cols =====
    // lane covers rows {wvi*32 + qd*8 + rp*2 + 0/1}, cols [l16*8, l16*8+8)
    {
        const float4* pws4 = (const float4*)pws;   // [30][32]
        const float4* peb4 = (const float4*)pebs;  // [32]
        float4 pbA = peb4[l16 * 2], pbB = peb4[l16 * 2 + 1];
        for (int rp = 0; rp < 4; rp++) {
            int rl = wvi * 32 + qd * 8 + rp * 2;
            float f0[30], f1[30];
            make_feats(qpts, row0 + rl, f0);
            make_feats(qpts, row0 + rl + 1, f1);
            float a0[8] = {pbA.x, pbA.y, pbA.z, pbA.w, pbB.x, pbB.y, pbB.z, pbB.w};
            float a1[8] = {pbA.x, pbA.y, pbA.z, pbA.w, pbB.x, pbB.y, pbB.z, pbB.w};
            #pragma unroll
            for (int ff = 0; ff < 30; ff++) {
                float4 wa = pws4[ff * 32 + l16 * 2];
                float4 wb = pws4[ff * 32 + l16 * 2 + 1];
                float v0 = f0[ff], v1 = f1[ff];
                a0[0] += v0 * wa.x; a0[1] += v0 * wa.y; a0[2] += v0 * wa.z; a0[3] += v0 * wa.w;
                a0[4] += v0 * wb.x; a0[5] += v0 * wb.y; a0[6] += v0 * wb.z; a0[7] += v0 * wb.w;
                a1[0] += v1 * wa.x; a1[1] += v1 * wa.y; a1[2] += v1 * wa.z; a1[3] += v1 * wa.w;
                a1[4] += v1 * wb.x; a1[5] += v1 * wb.y; a1[6] += v1 * wb.z; a1[7] += v1 * wb.w;
            }
            s8v h0, h1;
            #pragma unroll
            for (int j = 0; j < 8; j++) {
                h0[j] = (short)f2b_rne(__sinf(a0[j]));
                h1[j] = (short)f2b_rne(__sinf(a1[j]));
            }
            *(s8v*)&sA[rl * LDA + l16 * 8] = h0;
            *(s8v*)&sA[(rl + 1) * LDA + l16 * 8] = h1;
        }
    }

    // residual h in C-layout regs (bf16-rounded base; fp32 thereafter)
    float hres[2][4][8];
    #pragma unroll
    for (int tile = 0; tile < 2; tile++)
        #pragma unroll
        for (int i = 0; i < 4; i++)
            #pragma unroll
            for (int tc = 0; tc < 8; tc++)
                hres[tile][i][tc] =
                    b2f(sA[(r0c + tile * 16 + i) * LDA + tc * 16 + l16]);

    s8v af[2][4];

    // ===== 3 transformer layers (no barriers) =====
    for (int l = 0; l < 3; l++) {
        const float* bql = &biasAll[(l * 4 + 0) * 128];
        const float* bol = &biasAll[(l * 4 + 1) * 128];
        const float* b1l = &biasAll[(l * 4 + 2) * 128];
        const float* b2l = &biasAll[(l * 4 + 3) * 128];

        // mm1: qh = (h @ Wq + bq)^2 -> sA
        LOAD_AF(af);   // h
        RUN_MM(af, wqT + l * 16384, {
            int c = tc * 16 + l16;
            float bb = bql[c];
            _Pragma("unroll")
            for (int i = 0; i < 4; i++) {
                float v0 = x0[i] + bb;
                sA[(r0c + i) * LDA + c] = f2b_rne(v0 * v0);
                float v1 = x1[i] + bb;
                sA[(r0c + 16 + i) * LDA + c] = f2b_rne(v1 * v1);
            }
        });

        // den: dens[r][h] = qh_r . ksum_h   (B from LDS sKs)
        LOAD_AF(af);   // qh
        #pragma unroll
        for (int tile = 0; tile < 2; tile++) {
            f4v d = {0.f, 0.f, 0.f, 0.f};
            #pragma unroll
            for (int ks = 0; ks < 4; ks++) {
                s8v bf = *(const s8v*)&sKsAll[(l * 16 + l16) * LDA + ks * 32 + qd * 8];
                d = MFMA_BF16(af[tile][ks], bf, d, 0, 0, 0);
            }
            if (l16 < 4) {
                #pragma unroll
                for (int i = 0; i < 4; i++)
                    dens[(r0c + tile * 16 + i) * 4 + l16] = d[i];
            }
        }
        // scale qh fragments by z = 1/(den+1e-6); head of k-step ks == ks
        #pragma unroll
        for (int tile = 0; tile < 2; tile++) {
            int mr = rA0 + tile * 16;
            #pragma unroll
            for (int ks = 0; ks < 4; ks++) {
                float z = 1.f / (dens[mr * 4 + ks] + 1e-6f);
                #pragma unroll
                for (int j = 0; j < 8; j++) {
                    float q = b2f((unsigned short)af[tile][ks][j]);
                    af[tile][ks][j] = (short)f2b_rne(q * z);
                }
            }
        }

        // mm2: x = h + (z*qh) @ Wa + bo -> hres(fp32), sA(bf16)
        RUN_MM(af, waT + l * 16384, {
            int c = tc * 16 + l16;
            float bb = bol[c];
            _Pragma("unroll")
            for (int i = 0; i < 4; i++) {
                float v0 = hres[0][i][tc] + x0[i] + bb;
                hres[0][i][tc] = v0;
                sA[(r0c + i) * LDA + c] = f2b_rne(v0);
                float v1 = hres[1][i][tc] + x1[i] + bb;
                hres[1][i][tc] = v1;
                sA[(r0c + 16 + i) * LDA + c] = f2b_rne(v1);
            }
        });

        // mm3: t = gelu(x @ W1 + b1) -> sA
        LOAD_AF(af);   // x
        RUN_MM(af, w1T + l * 16384, {
            int c = tc * 16 + l16;
            float bb = b1l[c];
            _Pragma("unroll")
            for (int i = 0; i < 4; i++) {
                sA[(r0c + i) * LDA + c] = f2b_rne(gelu_t(x0[i] + bb));
                sA[(r0c + 16 + i) * LDA + c] = f2b_rne(gelu_t(x1[i] + bb));
            }
        });

        // mm4: h_new = x + t @ W2 + b2 -> hres, sA
        LOAD_AF(af);   // t
        RUN_MM(af, w2T + l * 16384, {
            int c = tc * 16 + l16;
            float bb = b2l[c];
            _Pragma("unroll")
            for (int i = 0; i < 4; i++) {
                float v0 = hres[0][i][tc] + x0[i] + bb;
                hres[0][i][tc] = v0;
                sA[(r0c + i) * LDA + c] = f2b_rne(v0);
                float v1 = hres[1][i][tc] + x1[i] + bb;
                hres[1][i][tc] = v1;
                sA[(r0c + 16 + i) * LDA + c] = f2b_rne(v1);
            }
        });
    }

    // ===== final projector: out = gelu(h @ pw1 + pb1) @ pw2 + pb2 =====
    {
        LOAD_AF(af);   // h final
        float* sAf = (float*)sA;   // [128][68] fp32 view (row = 272B = LDA)
        const unsigned short* base = pw1T + l16 * 128 + qd * 8;
        #pragma unroll
        for (int tc = 0; tc < 4; tc++) {
            s8v c0 = *(const s8v*)(base + tc * 2048);
            s8v c1 = *(const s8v*)(base + tc * 2048 + 32);
            s8v c2 = *(const s8v*)(base + tc * 2048 + 64);
            s8v c3 = *(const s8v*)(base + tc * 2048 + 96);
            f4v x0 = {0.f, 0.f, 0.f, 0.f}, x1 = {0.f, 0.f, 0.f, 0.f};
            x0 = MFMA_BF16(af[0][0], c0, x0, 0, 0, 0);
            x1 = MFMA_BF16(af[1][0], c0, x1, 0, 0, 0);
            x0 = MFMA_BF16(af[0][1], c1, x0, 0, 0, 0);
            x1 = MFMA_BF16(af[1][1], c1, x1, 0, 0, 0);
            x0 = MFMA_BF16(af[0][2], c2, x0, 0, 0, 0);
            x1 = MFMA_BF16(af[1][2], c2, x1, 0, 0, 0);
            x0 = MFMA_BF16(af[0][3], c3, x0, 0, 0, 0);
            x1 = MFMA_BF16(af[1][3], c3, x1, 0, 0, 0);
            int c = tc * 16 + l16;
            float bb = pb1s[c];
            #pragma unroll
            for (int i = 0; i < 4; i++) {
                sAf[(r0c + i) * 68 + c] = gelu_t(x0[i] + bb);
                sAf[(r0c + 16 + i) * 68 + c] = gelu_t(x1[i] + bb);
            }
        }
    }
    __syncthreads();   // barrier #2: cross-wave read below

    {
        const float* sAf = (const float*)sA;
        for (int idx = t; idx < 384; idx += 256) {
            int r = idx / 3, c = idx - r * 3;
            float s = pb2s[c];
            #pragma unroll 8
            for (int j = 0; j < 64; j++) s += sAf[r * 68 + j] * w2s[j * 3 + c];
            size_t o = (size_t)(row0 + r) * 3 + c;
            if (*flag) ((float*)outv)[o] = s;
            else       ((unsigned short*)outv)[o] = f2b(s);
        }
    }
}

// ---------- launch ----------
extern "C" void kernel_launch(void* const* d_in, const int* in_sizes, int n_in,
                              void* d_out, int out_size, void* d_ws, size_t ws_size,
                              hipStream_t stream) {
    const int N = in_sizes[0] / 2;   // 262144
    const int M = in_sizes[1] / 2;   // 4096

    ConvArgs ca;
    int total = 0;
    for (int i = 0; i < 22; i++) { ca.p[i] = d_in[i]; ca.off[i] = total; total += in_sizes[i]; }
    ca.off[22] = total;

    float* ws = (float*)d_ws;
    int* flag = (int*)ws;
    unsigned short* canon = (unsigned short*)(ws + 16);
    size_t canonF = ((size_t)(total + 1) / 2 + 15) & ~(size_t)15;
    float* b_enc = ws + 16 + canonF;                       // M*128
    float* khb   = b_enc + (size_t)M * 128;                // 12*M*32
    float* vhb   = khb + (size_t)12 * M * 32;              // 12*M*32
    float* kvs   = vhb + (size_t)12 * M * 32;              // 12288
    float* kss   = kvs + 12288;                            // 384
    unsigned short* wqT  = (unsigned short*)(kss + 384);   // 3*16384
    unsigned short* waT  = wqT + 49152;
    unsigned short* w1T  = waT + 49152;
    unsigned short* w2T  = w1T + 49152;
    unsigned short* ksT  = w2T + 49152;                    // 3*2048
    unsigned short* pw1T = ksT + 6144;                     // 8192

    const unsigned short* c_qpts = canon + ca.off[0];
    const unsigned short* c_bpts = canon + ca.off[1];
    const unsigned short* c_pew  = canon + ca.off[2];
    const unsigned short* c_peb  = canon + ca.off[3];
    const unsigned short* c_bpew = canon + ca.off[4];
    const unsigned short* c_bpeb = canon + ca.off[5];
    const unsigned short* c_Wq   = canon + ca.off[6];
    const unsigned short* c_bq   = canon + ca.off[7];
    const unsigned short* c_Wk   = canon + ca.off[8];
    const unsigned short* c_bk   = canon + ca.off[9];
    const unsigned short* c_Wv   = canon + ca.off[10];
    const unsigned short* c_bv   = canon + ca.off[11];
    const unsigned short* c_Wo   = canon + ca.off[12];
    const unsigned short* c_bo   = canon + ca.off[13];
    const unsigned short* c_W1   = canon + ca.off[14];
    const unsigned short* c_b1   = canon + ca.off[15];
    const unsigned short* c_W2   = canon + ca.off[16];
    const unsigned short* c_b2   = canon + ca.off[17];
    const unsigned short* c_pw1  = canon + ca.off[18];
    const unsigned short* c_pb1  = canon + ca.off[19];
    const unsigned short* c_pw2  = canon + ca.off[20];
    const unsigned short* c_pb2  = canon + ca.off[21];

    convert_kernel<<<(total + 255) / 256, 256, 0, stream>>>(
        ca, (const unsigned short*)d_in[2], flag, canon, total);

    encode_kernel<<<M / 8, 256, 0, stream>>>(c_bpts, c_bpew, c_bpeb, b_enc);
    khvh_kernel<<<(12 * M * 32) / 256, 256, 0, stream>>>(
        b_enc, c_Wk, c_bk, c_Wv, c_bv, khb, vhb, kvs);
    kvred_kernel<<<96, 1024, 0, stream>>>(khb, vhb, kvs, kss);
    prep_kernel<<<(210944 + 255) / 256, 256, 0, stream>>>(
        c_Wq, c_W1, c_W2, c_pw1, kvs, kss, c_Wo,
        wqT, w1T, w2T, pw1T, waT, ksT);

    mega_kernel<<<N / 128, 256, 0, stream>>>(
        c_qpts, c_pew, c_peb, wqT, waT, ksT, w1T, w2T,
        c_bq, c_bo, c_b1, c_b2, pw1T, c_pb1, c_pw2, c_pb2, d_out, flag);
}

// Round 8
// 729.688 us; speedup vs baseline: 1.1213x; 1.1213x over previous
//
#include <hip/hip_runtime.h>
#include <hip/hip_bf16.h>

// ---------- helpers ----------
__device__ __forceinline__ float b2f(unsigned short u) {
    return __uint_as_float(((unsigned)u) << 16);
}
__device__ __forceinline__ unsigned short f2b(float f) {
    __hip_bfloat16 h = __float2bfloat16(f);
    return *reinterpret_cast<unsigned short*>(&h);
}
// cheap round-to-nearest-even bf16 (no NaN inputs in this pipeline)
__device__ __forceinline__ unsigned short f2b_rne(float f) {
    unsigned u = __float_as_uint(f);
    return (unsigned short)((u + 0x7fffu + ((u >> 16) & 1u)) >> 16);
}
__device__ __forceinline__ float sigm(float v) {
    return 1.f / (1.f + __expf(-v));
}
// tanh-approx GELU (max abs dev from exact ~1e-3; post-W2 contribution <1e-3)
__device__ __forceinline__ float gelu_t(float x) {
    float y = 0.7978845608f * (x + 0.044715f * x * x * x);
    float e = __expf(2.f * y);
    float th = 1.f - 2.f / (e + 1.f);
    return 0.5f * x * (1.f + th);
}

typedef __attribute__((ext_vector_type(8))) short s8v;   // 8 bf16 (4 VGPRs)
typedef __attribute__((ext_vector_type(4))) float f4v;   // 4 fp32 acc

#define MFMA_BF16 __builtin_amdgcn_mfma_f32_16x16x32_bf16

// ---------- 15-feature map (per input coordinate) ----------
__device__ __forceinline__ void make_feats(const unsigned short* __restrict__ qpts,
                                           int r, float* __restrict__ f) {
    unsigned pq = *(const unsigned*)(qpts + (size_t)r * 2);
    float x0 = b2f((unsigned short)(pq & 0xffff));
    float x1 = b2f((unsigned short)(pq >> 16));
    const float PI = 3.14159265358979323846f;
    float a0 = x0 - 1.5f, a1 = x1 - 1.5f, c0 = x0 - 4.5f, c1 = x1 - 4.5f;
    f[0] = x0;        f[1] = x1;
    f[2] = x0 * x0;   f[3] = x1 * x1;
    f[4] = a0 * a0;   f[5] = a1 * a1;
    f[6] = c0 * c0;   f[7] = c1 * c1;
    f[8] = sigm(x0);  f[9] = sigm(x1);
    f[10] = sigm(a0); f[11] = sigm(a1);
    f[12] = sigm(c0); f[13] = sigm(c1);
    f[14] = a0;       f[15] = a1;
    f[16] = c0;       f[17] = c1;
    f[18] = __sinf(PI * x0);          f[19] = __sinf(PI * x1);
    f[20] = __cosf(PI * x0);          f[21] = __cosf(PI * x1);
    f[22] = __sinf(PI * 0.25f * x0);  f[23] = __sinf(PI * 0.25f * x1);
    f[24] = __cosf(PI * 0.25f * x0);  f[25] = __cosf(PI * 0.25f * x1);
    f[26] = __sinf(PI * 0.5f * x0);   f[27] = __sinf(PI * 0.5f * x1);
    f[28] = __cosf(PI * 0.5f * x0);   f[29] = __cosf(PI * 0.5f * x1);
}

// ---------- canonicalize all inputs to bf16 (embedded dtype detection) ----------
struct ConvArgs {
    const void* p[22];
    int off[23];
};

__global__ __launch_bounds__(256) void convert_kernel(
    ConvArgs a, const unsigned short* __restrict__ pe_w_raw,
    int* __restrict__ flag, unsigned short* __restrict__ canon, int total)
{
    __shared__ int cnt;
    if (threadIdx.x == 0) cnt = 0;
    __syncthreads();
    float v = b2f(pe_w_raw[threadIdx.x * 2]);
    if (!(fabsf(v) < 1.0f)) atomicAdd(&cnt, 1);
    __syncthreads();
    int isf32 = (cnt >= 16) ? 1 : 0;
    if (blockIdx.x == 0 && threadIdx.x == 0) *flag = isf32;

    int g = blockIdx.x * 256 + threadIdx.x;
    if (g >= total) return;
    int s = 0;
    #pragma unroll
    for (int i = 1; i < 23; i++) s += (g >= a.off[i]) ? 1 : 0;
    int local = g - a.off[s];
    unsigned short r;
    if (isf32) r = f2b(((const float*)a.p[s])[local]);
    else       r = ((const unsigned short*)a.p[s])[local];
    canon[g] = r;
}

// ---------- boundary positional encoding (M rows, fp32 out) ----------
__global__ __launch_bounds__(256) void encode_kernel(
    const unsigned short* __restrict__ pts,
    const unsigned short* __restrict__ w,
    const unsigned short* __restrict__ b,
    float* __restrict__ out)
{
    __shared__ __align__(16) float wsm[30 * 128];
    __shared__ float bs[128];
    int t = threadIdx.x;
    for (int i = t; i < 30 * 128; i += 256) wsm[i] = b2f(w[i]);
    if (t < 128) bs[t] = b2f(b[t]);
    __syncthreads();

    int r = blockIdx.x * 8 + (t >> 5);
    int j = t & 31;
    float f[30];
    make_feats(pts, r, f);
    float s0 = bs[j * 4 + 0], s1 = bs[j * 4 + 1], s2 = bs[j * 4 + 2], s3 = bs[j * 4 + 3];
    #pragma unroll
    for (int ff = 0; ff < 30; ff++) {
        float4 wv = *(const float4*)&wsm[ff * 128 + j * 4];
        float fv = f[ff];
        s0 += fv * wv.x; s1 += fv * wv.y; s2 += fv * wv.z; s3 += fv * wv.w;
    }
    *(float4*)&out[(size_t)r * 128 + j * 4] =
        make_float4(__sinf(s0), __sinf(s1), __sinf(s2), __sinf(s3));
}

// ---------- boundary k/v heads (+ zeroing of kv/ks accumulators) ----------
__global__ __launch_bounds__(256) void khvh_kernel(
    const float* __restrict__ benc,
    const unsigned short* __restrict__ Wk, const unsigned short* __restrict__ bk,
    const unsigned short* __restrict__ Wv, const unsigned short* __restrict__ bv,
    float* __restrict__ kh, float* __restrict__ vh, float* __restrict__ kvz)
{
    int g = blockIdx.x * 256 + threadIdx.x;
    if (g < 12672) kvz[g] = 0.f;   // kvs(12288) + kss(384), contiguous
    int lh = g >> 17;
    int rem = g & 131071;
    int m = rem >> 5;
    int dd = rem & 31;
    const unsigned short* wk = Wk + lh * 4096 + dd;
    const unsigned short* wv = Wv + lh * 4096 + dd;
    const float* br = benc + (size_t)m * 128;
    float ka = 0.f, va = 0.f;
    #pragma unroll 8
    for (int c = 0; c < 128; c++) {
        float bb = br[c];
        ka += bb * b2f(wk[c * 32]);
        va += bb * b2f(wv[c * 32]);
    }
    ka += b2f(bk[lh * 32 + dd]); ka = ka * ka;
    va += b2f(bv[lh * 32 + dd]);
    kh[g] = ka; vh[g] = va;
}

// ---------- reduce over boundary points: kvsum[lh][d][e], ksum[lh][d] ----------
__global__ __launch_bounds__(1024) void kvred_kernel(
    const float* __restrict__ kh, const float* __restrict__ vh,
    float* __restrict__ kvsum, float* __restrict__ ksum)
{
    __shared__ float khs[1024];
    __shared__ float vhs[1024];
    int t = threadIdx.x;
    int lh = blockIdx.x >> 3;
    int part = blockIdx.x & 7;
    int dd = t >> 5, ee = t & 31;
    float kva = 0.f, ksa = 0.f;
    for (int ch = 0; ch < 16; ch++) {
        int base = lh * 131072 + (part * 16 + ch) * 1024;
        khs[t] = kh[base + t];
        vhs[t] = vh[base + t];
        __syncthreads();
        #pragma unroll
        for (int i = 0; i < 32; i++) {
            float kk = khs[i * 32 + dd];
            kva += kk * vhs[i * 32 + ee];
            ksa += kk;
        }
        __syncthreads();
    }
    atomicAdd(&kvsum[lh * 1024 + dd * 32 + ee], kva);
    if (ee == 0) atomicAdd(&ksum[lh * 32 + dd], ksa);
}

// ---------- prep: transposes + Wa fold + Ks matrix, one kernel ----------
__global__ __launch_bounds__(256) void prep_kernel(
    const unsigned short* __restrict__ Wq, const unsigned short* __restrict__ W1,
    const unsigned short* __restrict__ W2, const unsigned short* __restrict__ pw1,
    const float* __restrict__ kvs, const float* __restrict__ kss,
    const unsigned short* __restrict__ Wo,
    unsigned short* __restrict__ wqT, unsigned short* __restrict__ w1T,
    unsigned short* __restrict__ w2T, unsigned short* __restrict__ pw1T,
    unsigned short* __restrict__ waT, unsigned short* __restrict__ ksT)
{
    int g = blockIdx.x * 256 + threadIdx.x;
    if (g < 49152) {
        int l = g >> 14, r = g & 16383, n = r >> 7, k = r & 127;
        wqT[g] = Wq[((l * 4 + (n >> 5)) * 128 + k) * 32 + (n & 31)];  // head-interleaved cols
    } else if (g < 98304) {
        int q = g - 49152; int l = q >> 14, r = q & 16383, n = r >> 7, k = r & 127;
        w1T[q] = W1[(l * 128 + k) * 128 + n];
    } else if (g < 147456) {
        int q = g - 98304; int l = q >> 14, r = q & 16383, n = r >> 7, k = r & 127;
        w2T[q] = W2[(l * 128 + k) * 128 + n];
    } else if (g < 155648) {
        int q = g - 147456; int n = q >> 7, k = q & 127;
        pw1T[q] = pw1[k * 64 + n];
    } else if (g < 204800) {
        int q = g - 155648; int l = q >> 14, r = q & 16383, n = r >> 7, k = r & 127;
        int hk = k >> 5, dk = k & 31;
        const float* kvp = kvs + (l * 4 + hk) * 1024 + dk * 32;
        const unsigned short* wop = Wo + (size_t)(l * 128 + hk * 32) * 128 + n;
        float s = 0.f;
        #pragma unroll 8
        for (int j = 0; j < 32; j++) s += kvp[j] * b2f(wop[j * 128]);
        waT[q] = f2b(s);
    } else if (g < 210944) {
        int q = g - 204800; int l = q >> 11, r = q & 2047, n = r >> 7, k = r & 127;
        unsigned short v = 0;
        if (n < 4 && (k >> 5) == n) v = f2b(kss[(l * 4 + n) * 32 + (k & 31)]);
        ksT[q] = v;
    }
}

// ---------- the fused mega kernel: encode + 3 layers + projector ----------
// 128 rows/block, 4 waves; wave w owns rows [w*32, w*32+32) = 2 MFMA row-tiles.
// Weights read as B-fragments DIRECTLY FROM GLOBAL (L2-hot), no barriers in
// the layer loop (activations wave-private; same-wave LDS ops are in order).
// NOTE: __launch_bounds__(256) with NO min-waves arg. Rounds 5/7 used
// (256,2): that caps the per-wave arch-VGPR budget at 128 (512-reg pool /
// 2 waves, minus AGPR split on the unified file) -> hres[2][4][8] spilled
// to scratch -> 860 MB HBM spill traffic, MfmaUtil 7%. LDS (73 KB) already
// limits to 2 blocks/CU; the register cap bought nothing. Round 4 precedent:
// launch_bounds(256) -> VGPR 164, zero spill.
#define LDA 136   // LDS row stride in ushorts (272B = 17*16B)

// mm over 8 col-tiles of a 128x128 [n][k] weight matrix; B-frags from global
// with prefetch-1. EPI sees: tc, x0 (rows r0c..+3), x1 (rows r0c+16..+19).
#define RUN_MM(AF, W, ...) do {                                               \
    const unsigned short* _base = (W) + l16 * 128 + qd * 8;                   \
    s8v _c0 = *(const s8v*)(_base);                                           \
    s8v _c1 = *(const s8v*)(_base + 32);                                      \
    s8v _c2 = *(const s8v*)(_base + 64);                                      \
    s8v _c3 = *(const s8v*)(_base + 96);                                      \
    _Pragma("unroll")                                                         \
    for (int tc = 0; tc < 8; tc++) {                                          \
        s8v _n0, _n1, _n2, _n3;                                               \
        if (tc < 7) {                                                         \
            const unsigned short* _bp = _base + (tc + 1) * 2048;              \
            _n0 = *(const s8v*)(_bp);      _n1 = *(const s8v*)(_bp + 32);     \
            _n2 = *(const s8v*)(_bp + 64); _n3 = *(const s8v*)(_bp + 96);     \
        }                                                                     \
        f4v x0 = {0.f, 0.f, 0.f, 0.f}, x1 = {0.f, 0.f, 0.f, 0.f};             \
        x0 = MFMA_BF16(AF[0][0], _c0, x0, 0, 0, 0);                           \
        x1 = MFMA_BF16(AF[1][0], _c0, x1, 0, 0, 0);                           \
        x0 = MFMA_BF16(AF[0][1], _c1, x0, 0, 0, 0);                           \
        x1 = MFMA_BF16(AF[1][1], _c1, x1, 0, 0, 0);                           \
        x0 = MFMA_BF16(AF[0][2], _c2, x0, 0, 0, 0);                           \
        x1 = MFMA_BF16(AF[1][2], _c2, x1, 0, 0, 0);                           \
        x0 = MFMA_BF16(AF[0][3], _c3, x0, 0, 0, 0);                           \
        x1 = MFMA_BF16(AF[1][3], _c3, x1, 0, 0, 0);                           \
        { __VA_ARGS__ }                                                       \
        if (tc < 7) { _c0 = _n0; _c1 = _n1; _c2 = _n2; _c3 = _n3; }           \
    }                                                                         \
} while (0)

// load A-fragments (2 row-tiles) for this wave's rows from sA
#define LOAD_AF(AF) do {                                                      \
    _Pragma("unroll")                                                         \
    for (int _t = 0; _t < 2; _t++)                                            \
        _Pragma("unroll")                                                     \
        for (int _k = 0; _k < 4; _k++)                                        \
            AF[_t][_k] = *(const s8v*)&sA[(rA0 + _t * 16) * LDA + _k * 32 + qd * 8]; \
} while (0)

__global__ __launch_bounds__(256) void mega_kernel(
    const unsigned short* __restrict__ qpts,
    const unsigned short* __restrict__ pe_w,
    const unsigned short* __restrict__ pe_b,
    const unsigned short* __restrict__ wqT,
    const unsigned short* __restrict__ waT,
    const unsigned short* __restrict__ ksT,
    const unsigned short* __restrict__ w1T,
    const unsigned short* __restrict__ w2T,
    const unsigned short* __restrict__ bq,
    const unsigned short* __restrict__ bo,
    const unsigned short* __restrict__ b1,
    const unsigned short* __restrict__ b2,
    const unsigned short* __restrict__ pw1T,
    const unsigned short* __restrict__ pb1,
    const unsigned short* __restrict__ pw2,
    const unsigned short* __restrict__ pb2,
    void* __restrict__ outv, const int* __restrict__ flag)
{
    __shared__ __align__(16) unsigned short sA[128 * LDA];   // 34816 B activations
    __shared__ __align__(16) float pws[30 * 128];            // 15360 B
    __shared__ __align__(16) unsigned short sKsAll[3 * 16 * LDA]; // 13056 B
    __shared__ float biasAll[12 * 128];                      // 6144 B [l][{q,o,1,2}][c]
    __shared__ float pebs[128];
    __shared__ float pb1s[64];
    __shared__ float w2s[192];
    __shared__ float pb2s[3];
    __shared__ float dens[128 * 4];                          // 2048 B

    int t = threadIdx.x;
    int wvi = t >> 6, ln = t & 63, qd = ln >> 4, l16 = ln & 15;
    int row0 = blockIdx.x * 128;
    int rA0 = wvi * 32 + l16;        // A-frag row, tile 0 (tile 1: +16)
    int r0c = wvi * 32 + qd * 4;     // C base row, tile 0 (tile 1: +16)

    // ===== one-time staging =====
    for (int i = t; i < 3840; i += 256) pws[i] = b2f(pe_w[i]);
    #pragma unroll
    for (int ll = 0; ll < 3; ll++)
        *(int4*)&sKsAll[(ll * 16 + (t >> 4)) * LDA + (t & 15) * 8] =
            ((const int4*)(ksT + ll * 2048))[t];
    for (int i = t; i < 1536; i += 256) {
        int l = i >> 9, rem = i & 511, which = rem >> 7, c = rem & 127;
        const unsigned short* bsrc = (which == 0) ? bq : (which == 1) ? bo
                                   : (which == 2) ? b1 : b2;
        biasAll[i] = b2f(bsrc[l * 128 + c]);
    }
    if (t < 128) pebs[t] = b2f(pe_b[t]);
    if (t < 64)  pb1s[t] = b2f(pb1[t]);
    if (t < 192) w2s[t] = b2f(pw2[t]);
    if (t < 3)   pb2s[t] = b2f(pb2[t]);
    __syncthreads();     // barrier #1 (the only one before the tail)

    // ===== encode: h = sin(feats @ pe_w + pe_b), vectorized cols =====
    // lane covers rows {wvi*32 + qd*8 + rp*2 + 0/1}, cols [l16*8, l16*8+8)
    {
        const float4* pws4 = (const float4*)pws;   // [30][32]
        const float4* peb4 = (const float4*)pebs;  // [32]
        float4 pbA = peb4[l16 * 2], pbB = peb4[l16 * 2 + 1];
        for (int rp = 0; rp < 4; rp++) {
            int rl = wvi * 32 + qd * 8 + rp * 2;
            float f0[30], f1[30];
            make_feats(qpts, row0 + rl, f0);
            make_feats(qpts, row0 + rl + 1, f1);
            float a0[8] = {pbA.x, pbA.y, pbA.z, pbA.w, pbB.x, pbB.y, pbB.z, pbB.w};
            float a1[8] = {pbA.x, pbA.y, pbA.z, pbA.w, pbB.x, pbB.y, pbB.z, pbB.w};
            #pragma unroll
            for (int ff = 0; ff < 30; ff++) {
                float4 wa = pws4[ff * 32 + l16 * 2];
                float4 wb = pws4[ff * 32 + l16 * 2 + 1];
                float v0 = f0[ff], v1 = f1[ff];
                a0[0] += v0 * wa.x; a0[1] += v0 * wa.y; a0[2] += v0 * wa.z; a0[3] += v0 * wa.w;
                a0[4] += v0 * wb.x; a0[5] += v0 * wb.y; a0[6] += v0 * wb.z; a0[7] += v0 * wb.w;
                a1[0] += v1 * wa.x; a1[1] += v1 * wa.y; a1[2] += v1 * wa.z; a1[3] += v1 * wa.w;
                a1[4] += v1 * wb.x; a1[5] += v1 * wb.y; a1[6] += v1 * wb.z; a1[7] += v1 * wb.w;
            }
            s8v h0, h1;
            #pragma unroll
            for (int j = 0; j < 8; j++) {
                h0[j] = (short)f2b_rne(__sinf(a0[j]));
                h1[j] = (short)f2b_rne(__sinf(a1[j]));
            }
            *(s8v*)&sA[rl * LDA + l16 * 8] = h0;
            *(s8v*)&sA[(rl + 1) * LDA + l16 * 8] = h1;
        }
    }

    // residual h in C-layout regs (bf16-rounded base; fp32 thereafter)
    float hres[2][4][8];
    #pragma unroll
    for (int tile = 0; tile < 2; tile++)
        #pragma unroll
        for (int i = 0; i < 4; i++)
            #pragma unroll
            for (int tc = 0; tc < 8; tc++)
                hres[tile][i][tc] =
                    b2f(sA[(r0c + tile * 16 + i) * LDA + tc * 16 + l16]);

    s8v af[2][4];

    // ===== 3 transformer layers (no barriers) =====
    for (int l = 0; l < 3; l++) {
        const float* bql = &biasAll[(l * 4 + 0) * 128];
        const float* bol = &biasAll[(l * 4 + 1) * 128];
        const float* b1l = &biasAll[(l * 4 + 2) * 128];
        const float* b2l = &biasAll[(l * 4 + 3) * 128];

        // mm1: qh = (h @ Wq + bq)^2 -> sA
        LOAD_AF(af);   // h
        RUN_MM(af, wqT + l * 16384, {
            int c = tc * 16 + l16;
            float bb = bql[c];
            _Pragma("unroll")
            for (int i = 0; i < 4; i++) {
                float v0 = x0[i] + bb;
                sA[(r0c + i) * LDA + c] = f2b_rne(v0 * v0);
                float v1 = x1[i] + bb;
                sA[(r0c + 16 + i) * LDA + c] = f2b_rne(v1 * v1);
            }
        });

        // den: dens[r][h] = qh_r . ksum_h   (B from LDS sKs)
        LOAD_AF(af);   // qh
        #pragma unroll
        for (int tile = 0; tile < 2; tile++) {
            f4v d = {0.f, 0.f, 0.f, 0.f};
            #pragma unroll
            for (int ks = 0; ks < 4; ks++) {
                s8v bf = *(const s8v*)&sKsAll[(l * 16 + l16) * LDA + ks * 32 + qd * 8];
                d = MFMA_BF16(af[tile][ks], bf, d, 0, 0, 0);
            }
            if (l16 < 4) {
                #pragma unroll
                for (int i = 0; i < 4; i++)
                    dens[(r0c + tile * 16 + i) * 4 + l16] = d[i];
            }
        }
        // scale qh fragments by z = 1/(den+1e-6); head of k-step ks == ks
        #pragma unroll
        for (int tile = 0; tile < 2; tile++) {
            int mr = rA0 + tile * 16;
            #pragma unroll
            for (int ks = 0; ks < 4; ks++) {
                float z = 1.f / (dens[mr * 4 + ks] + 1e-6f);
                #pragma unroll
                for (int j = 0; j < 8; j++) {
                    float q = b2f((unsigned short)af[tile][ks][j]);
                    af[tile][ks][j] = (short)f2b_rne(q * z);
                }
            }
        }

        // mm2: x = h + (z*qh) @ Wa + bo -> hres(fp32), sA(bf16)
        RUN_MM(af, waT + l * 16384, {
            int c = tc * 16 + l16;
            float bb = bol[c];
            _Pragma("unroll")
            for (int i = 0; i < 4; i++) {
                float v0 = hres[0][i][tc] + x0[i] + bb;
                hres[0][i][tc] = v0;
                sA[(r0c + i) * LDA + c] = f2b_rne(v0);
                float v1 = hres[1][i][tc] + x1[i] + bb;
                hres[1][i][tc] = v1;
                sA[(r0c + 16 + i) * LDA + c] = f2b_rne(v1);
            }
        });

        // mm3: t = gelu(x @ W1 + b1) -> sA
        LOAD_AF(af);   // x
        RUN_MM(af, w1T + l * 16384, {
            int c = tc * 16 + l16;
            float bb = b1l[c];
            _Pragma("unroll")
            for (int i = 0; i < 4; i++) {
                sA[(r0c + i) * LDA + c] = f2b_rne(gelu_t(x0[i] + bb));
                sA[(r0c + 16 + i) * LDA + c] = f2b_rne(gelu_t(x1[i] + bb));
            }
        });

        // mm4: h_new = x + t @ W2 + b2 -> hres, sA
        LOAD_AF(af);   // t
        RUN_MM(af, w2T + l * 16384, {
            int c = tc * 16 + l16;
            float bb = b2l[c];
            _Pragma("unroll")
            for (int i = 0; i < 4; i++) {
                float v0 = hres[0][i][tc] + x0[i] + bb;
                hres[0][i][tc] = v0;
                sA[(r0c + i) * LDA + c] = f2b_rne(v0);
                float v1 = hres[1][i][tc] + x1[i] + bb;
                hres[1][i][tc] = v1;
                sA[(r0c + 16 + i) * LDA + c] = f2b_rne(v1);
            }
        });
    }

    // ===== final projector: out = gelu(h @ pw1 + pb1) @ pw2 + pb2 =====
    {
        LOAD_AF(af);   // h final
        float* sAf = (float*)sA;   // [128][68] fp32 view (row = 272B = LDA)
        const unsigned short* base = pw1T + l16 * 128 + qd * 8;
        #pragma unroll
        for (int tc = 0; tc < 4; tc++) {
            s8v c0 = *(const s8v*)(base + tc * 2048);
            s8v c1 = *(const s8v*)(base + tc * 2048 + 32);
            s8v c2 = *(const s8v*)(base + tc * 2048 + 64);
            s8v c3 = *(const s8v*)(base + tc * 2048 + 96);
            f4v x0 = {0.f, 0.f, 0.f, 0.f}, x1 = {0.f, 0.f, 0.f, 0.f};
            x0 = MFMA_BF16(af[0][0], c0, x0, 0, 0, 0);
            x1 = MFMA_BF16(af[1][0], c0, x1, 0, 0, 0);
            x0 = MFMA_BF16(af[0][1], c1, x0, 0, 0, 0);
            x1 = MFMA_BF16(af[1][1], c1, x1, 0, 0, 0);
            x0 = MFMA_BF16(af[0][2], c2, x0, 0, 0, 0);
            x1 = MFMA_BF16(af[1][2], c2, x1, 0, 0, 0);
            x0 = MFMA_BF16(af[0][3], c3, x0, 0, 0, 0);
            x1 = MFMA_BF16(af[1][3], c3, x1, 0, 0, 0);
            int c = tc * 16 + l16;
            float bb = pb1s[c];
            #pragma unroll
            for (int i = 0; i < 4; i++) {
                sAf[(r0c + i) * 68 + c] = gelu_t(x0[i] + bb);
                sAf[(r0c + 16 + i) * 68 + c] = gelu_t(x1[i] + bb);
            }
        }
    }
    __syncthreads();   // barrier #2: cross-wave read below

    {
        const float* sAf = (const float*)sA;
        for (int idx = t; idx < 384; idx += 256) {
            int r = idx / 3, c = idx - r * 3;
            float s = pb2s[c];
            #pragma unroll 8
            for (int j = 0; j < 64; j++) s += sAf[r * 68 + j] * w2s[j * 3 + c];
            size_t o = (size_t)(row0 + r) * 3 + c;
            if (*flag) ((float*)outv)[o] = s;
            else       ((unsigned short*)outv)[o] = f2b(s);
        }
    }
}

// ---------- launch ----------
extern "C" void kernel_launch(void* const* d_in, const int* in_sizes, int n_in,
                              void* d_out, int out_size, void* d_ws, size_t ws_size,
                              hipStream_t stream) {
    const int N = in_sizes[0] / 2;   // 262144
    const int M = in_sizes[1] / 2;   // 4096

    ConvArgs ca;
    int total = 0;
    for (int i = 0; i < 22; i++) { ca.p[i] = d_in[i]; ca.off[i] = total; total += in_sizes[i]; }
    ca.off[22] = total;

    float* ws = (float*)d_ws;
    int* flag = (int*)ws;
    unsigned short* canon = (unsigned short*)(ws + 16);
    size_t canonF = ((size_t)(total + 1) / 2 + 15) & ~(size_t)15;
    float* b_enc = ws + 16 + canonF;                       // M*128
    float* khb   = b_enc + (size_t)M * 128;                // 12*M*32
    float* vhb   = khb + (size_t)12 * M * 32;              // 12*M*32
    float* kvs   = vhb + (size_t)12 * M * 32;              // 12288
    float* kss   = kvs + 12288;                            // 384
    unsigned short* wqT  = (unsigned short*)(kss + 384);   // 3*16384
    unsigned short* waT  = wqT + 49152;
    unsigned short* w1T  = waT + 49152;
    unsigned short* w2T  = w1T + 49152;
    unsigned short* ksT  = w2T + 49152;                    // 3*2048
    unsigned short* pw1T = ksT + 6144;                     // 8192

    const unsigned short* c_qpts = canon + ca.off[0];
    const unsigned short* c_bpts = canon + ca.off[1];
    const unsigned short* c_pew  = canon + ca.off[2];
    const unsigned short* c_peb  = canon + ca.off[3];
    const unsigned short* c_bpew = canon + ca.off[4];
    const unsigned short* c_bpeb = canon + ca.off[5];
    const unsigned short* c_Wq   = canon + ca.off[6];
    const unsigned short* c_bq   = canon + ca.off[7];
    const unsigned short* c_Wk   = canon + ca.off[8];
    const unsigned short* c_bk   = canon + ca.off[9];
    const unsigned short* c_Wv   = canon + ca.off[10];
    const unsigned short* c_bv   = canon + ca.off[11];
    const unsigned short* c_Wo   = canon + ca.off[12];
    const unsigned short* c_bo   = canon + ca.off[13];
    const unsigned short* c_W1   = canon + ca.off[14];
    const unsigned short* c_b1   = canon + ca.off[15];
    const unsigned short* c_W2   = canon + ca.off[16];
    const unsigned short* c_b2   = canon + ca.off[17];
    const unsigned short* c_pw1  = canon + ca.off[18];
    const unsigned short* c_pb1  = canon + ca.off[19];
    const unsigned short* c_pw2  = canon + ca.off[20];
    const unsigned short* c_pb2  = canon + ca.off[21];

    convert_kernel<<<(total + 255) / 256, 256, 0, stream>>>(
        ca, (const unsigned short*)d_in[2], flag, canon, total);

    encode_kernel<<<M / 8, 256, 0, stream>>>(c_bpts, c_bpew, c_bpeb, b_enc);
    khvh_kernel<<<(12 * M * 32) / 256, 256, 0, stream>>>(
        b_enc, c_Wk, c_bk, c_Wv, c_bv, khb, vhb, kvs);
    kvred_kernel<<<96, 1024, 0, stream>>>(khb, vhb, kvs, kss);
    prep_kernel<<<(210944 + 255) / 256, 256, 0, stream>>>(
        c_Wq, c_W1, c_W2, c_pw1, kvs, kss, c_Wo,
        wqT, w1T, w2T, pw1T, waT, ksT);

    mega_kernel<<<N / 128, 256, 0, stream>>>(
        c_qpts, c_pew, c_peb, wqT, waT, ksT, w1T, w2T,
        c_bq, c_bo, c_b1, c_b2, pw1T, c_pb1, c_pw2, c_pb2, d_out, flag);
}

// Round 9
// 644.719 us; speedup vs baseline: 1.2690x; 1.1318x over previous
//
#include <hip/hip_runtime.h>
#include <hip/hip_bf16.h>

// ---------- helpers ----------
__device__ __forceinline__ float b2f(unsigned short u) {
    return __uint_as_float(((unsigned)u) << 16);
}
__device__ __forceinline__ unsigned short f2b(float f) {
    __hip_bfloat16 h = __float2bfloat16(f);
    return *reinterpret_cast<unsigned short*>(&h);
}
// cheap round-to-nearest-even bf16 (no NaN inputs in this pipeline)
__device__ __forceinline__ unsigned short f2b_rne(float f) {
    unsigned u = __float_as_uint(f);
    return (unsigned short)((u + 0x7fffu + ((u >> 16) & 1u)) >> 16);
}
__device__ __forceinline__ float sigm(float v) {
    return 1.f / (1.f + __expf(-v));
}
// tanh-approx GELU (max abs dev from exact ~1e-3; post-W2 contribution <1e-3)
__device__ __forceinline__ float gelu_t(float x) {
    float y = 0.7978845608f * (x + 0.044715f * x * x * x);
    float e = __expf(2.f * y);
    float th = 1.f - 2.f / (e + 1.f);
    return 0.5f * x * (1.f + th);
}

typedef __attribute__((ext_vector_type(8))) short s8v;   // 8 bf16 (4 VGPRs)
typedef __attribute__((ext_vector_type(4))) float f4v;   // 4 fp32 acc

#define MFMA_BF16 __builtin_amdgcn_mfma_f32_16x16x32_bf16

// ---------- 15-feature map (full, for the boundary path) ----------
__device__ __forceinline__ void make_feats(const unsigned short* __restrict__ qpts,
                                           int r, float* __restrict__ f) {
    unsigned pq = *(const unsigned*)(qpts + (size_t)r * 2);
    float x0 = b2f((unsigned short)(pq & 0xffff));
    float x1 = b2f((unsigned short)(pq >> 16));
    const float PI = 3.14159265358979323846f;
    float a0 = x0 - 1.5f, a1 = x1 - 1.5f, c0 = x0 - 4.5f, c1 = x1 - 4.5f;
    f[0] = x0;        f[1] = x1;
    f[2] = x0 * x0;   f[3] = x1 * x1;
    f[4] = a0 * a0;   f[5] = a1 * a1;
    f[6] = c0 * c0;   f[7] = c1 * c1;
    f[8] = sigm(x0);  f[9] = sigm(x1);
    f[10] = sigm(a0); f[11] = sigm(a1);
    f[12] = sigm(c0); f[13] = sigm(c1);
    f[14] = a0;       f[15] = a1;
    f[16] = c0;       f[17] = c1;
    f[18] = __sinf(PI * x0);          f[19] = __sinf(PI * x1);
    f[20] = __cosf(PI * x0);          f[21] = __cosf(PI * x1);
    f[22] = __sinf(PI * 0.25f * x0);  f[23] = __sinf(PI * 0.25f * x1);
    f[24] = __cosf(PI * 0.25f * x0);  f[25] = __cosf(PI * 0.25f * x1);
    f[26] = __sinf(PI * 0.5f * x0);   f[27] = __sinf(PI * 0.5f * x1);
    f[28] = __cosf(PI * 0.5f * x0);   f[29] = __cosf(PI * 0.5f * x1);
}

// 8 features for k = qd*8 .. qd*8+7 (quad-split of the 30-vector, 30/31 -> 0)
__device__ __forceinline__ void feats8(unsigned pq, int qd, float* __restrict__ f8) {
    float x0 = b2f((unsigned short)(pq & 0xffff));
    float x1 = b2f((unsigned short)(pq >> 16));
    const float PI = 3.14159265358979323846f;
    float a0 = x0 - 1.5f, a1 = x1 - 1.5f, c0 = x0 - 4.5f, c1 = x1 - 4.5f;
    if (qd == 0) {
        f8[0] = x0;      f8[1] = x1;
        f8[2] = x0 * x0; f8[3] = x1 * x1;
        f8[4] = a0 * a0; f8[5] = a1 * a1;
        f8[6] = c0 * c0; f8[7] = c1 * c1;
    } else if (qd == 1) {
        f8[0] = sigm(x0); f8[1] = sigm(x1);
        f8[2] = sigm(a0); f8[3] = sigm(a1);
        f8[4] = sigm(c0); f8[5] = sigm(c1);
        f8[6] = a0;       f8[7] = a1;
    } else if (qd == 2) {
        f8[0] = c0; f8[1] = c1;
        f8[2] = __sinf(PI * x0);          f8[3] = __sinf(PI * x1);
        f8[4] = __cosf(PI * x0);          f8[5] = __cosf(PI * x1);
        f8[6] = __sinf(PI * 0.25f * x0);  f8[7] = __sinf(PI * 0.25f * x1);
    } else {
        f8[0] = __cosf(PI * 0.25f * x0);  f8[1] = __cosf(PI * 0.25f * x1);
        f8[2] = __sinf(PI * 0.5f * x0);   f8[3] = __sinf(PI * 0.5f * x1);
        f8[4] = __cosf(PI * 0.5f * x0);   f8[5] = __cosf(PI * 0.5f * x1);
        f8[6] = 0.f;                      f8[7] = 0.f;
    }
}

// ---------- canonicalize all inputs to bf16 (embedded dtype detection) ----------
struct ConvArgs {
    const void* p[22];
    int off[23];
};

__global__ __launch_bounds__(256) void convert_kernel(
    ConvArgs a, const unsigned short* __restrict__ pe_w_raw,
    int* __restrict__ flag, unsigned short* __restrict__ canon, int total)
{
    __shared__ int cnt;
    if (threadIdx.x == 0) cnt = 0;
    __syncthreads();
    float v = b2f(pe_w_raw[threadIdx.x * 2]);
    if (!(fabsf(v) < 1.0f)) atomicAdd(&cnt, 1);
    __syncthreads();
    int isf32 = (cnt >= 16) ? 1 : 0;
    if (blockIdx.x == 0 && threadIdx.x == 0) *flag = isf32;

    int g = blockIdx.x * 256 + threadIdx.x;
    if (g >= total) return;
    int s = 0;
    #pragma unroll
    for (int i = 1; i < 23; i++) s += (g >= a.off[i]) ? 1 : 0;
    int local = g - a.off[s];
    unsigned short r;
    if (isf32) r = f2b(((const float*)a.p[s])[local]);
    else       r = ((const unsigned short*)a.p[s])[local];
    canon[g] = r;
}

// ---------- boundary positional encoding (M rows, fp32 out) ----------
__global__ __launch_bounds__(256) void encode_kernel(
    const unsigned short* __restrict__ pts,
    const unsigned short* __restrict__ w,
    const unsigned short* __restrict__ b,
    float* __restrict__ out)
{
    __shared__ __align__(16) float wsm[30 * 128];
    __shared__ float bs[128];
    int t = threadIdx.x;
    for (int i = t; i < 30 * 128; i += 256) wsm[i] = b2f(w[i]);
    if (t < 128) bs[t] = b2f(b[t]);
    __syncthreads();

    int r = blockIdx.x * 8 + (t >> 5);
    int j = t & 31;
    float f[30];
    make_feats(pts, r, f);
    float s0 = bs[j * 4 + 0], s1 = bs[j * 4 + 1], s2 = bs[j * 4 + 2], s3 = bs[j * 4 + 3];
    #pragma unroll
    for (int ff = 0; ff < 30; ff++) {
        float4 wv = *(const float4*)&wsm[ff * 128 + j * 4];
        float fv = f[ff];
        s0 += fv * wv.x; s1 += fv * wv.y; s2 += fv * wv.z; s3 += fv * wv.w;
    }
    *(float4*)&out[(size_t)r * 128 + j * 4] =
        make_float4(__sinf(s0), __sinf(s1), __sinf(s2), __sinf(s3));
}

// ---------- boundary k/v heads (+ zeroing of kv/ks accumulators) ----------
__global__ __launch_bounds__(256) void khvh_kernel(
    const float* __restrict__ benc,
    const unsigned short* __restrict__ Wk, const unsigned short* __restrict__ bk,
    const unsigned short* __restrict__ Wv, const unsigned short* __restrict__ bv,
    float* __restrict__ kh, float* __restrict__ vh, float* __restrict__ kvz)
{
    int g = blockIdx.x * 256 + threadIdx.x;
    if (g < 12672) kvz[g] = 0.f;   // kvs(12288) + kss(384), contiguous
    int lh = g >> 17;
    int rem = g & 131071;
    int m = rem >> 5;
    int dd = rem & 31;
    const unsigned short* wk = Wk + lh * 4096 + dd;
    const unsigned short* wv = Wv + lh * 4096 + dd;
    const float* br = benc + (size_t)m * 128;
    float ka = 0.f, va = 0.f;
    #pragma unroll 8
    for (int c = 0; c < 128; c++) {
        float bb = br[c];
        ka += bb * b2f(wk[c * 32]);
        va += bb * b2f(wv[c * 32]);
    }
    ka += b2f(bk[lh * 32 + dd]); ka = ka * ka;
    va += b2f(bv[lh * 32 + dd]);
    kh[g] = ka; vh[g] = va;
}

// ---------- reduce over boundary points: kvsum[lh][d][e], ksum[lh][d] ----------
__global__ __launch_bounds__(1024) void kvred_kernel(
    const float* __restrict__ kh, const float* __restrict__ vh,
    float* __restrict__ kvsum, float* __restrict__ ksum)
{
    __shared__ float khs[1024];
    __shared__ float vhs[1024];
    int t = threadIdx.x;
    int lh = blockIdx.x >> 3;
    int part = blockIdx.x & 7;
    int dd = t >> 5, ee = t & 31;
    float kva = 0.f, ksa = 0.f;
    for (int ch = 0; ch < 16; ch++) {
        int base = lh * 131072 + (part * 16 + ch) * 1024;
        khs[t] = kh[base + t];
        vhs[t] = vh[base + t];
        __syncthreads();
        #pragma unroll
        for (int i = 0; i < 32; i++) {
            float kk = khs[i * 32 + dd];
            kva += kk * vhs[i * 32 + ee];
            ksa += kk;
        }
        __syncthreads();
    }
    atomicAdd(&kvsum[lh * 1024 + dd * 32 + ee], kva);
    if (ee == 0) atomicAdd(&ksum[lh * 32 + dd], ksa);
}

// ---------- prep: transposes + Wa fold + Ks + padded pe_wT, one kernel ----------
__global__ __launch_bounds__(256) void prep_kernel(
    const unsigned short* __restrict__ Wq, const unsigned short* __restrict__ W1,
    const unsigned short* __restrict__ W2, const unsigned short* __restrict__ pw1,
    const float* __restrict__ kvs, const float* __restrict__ kss,
    const unsigned short* __restrict__ Wo, const unsigned short* __restrict__ pe_w,
    unsigned short* __restrict__ wqT, unsigned short* __restrict__ w1T,
    unsigned short* __restrict__ w2T, unsigned short* __restrict__ pw1T,
    unsigned short* __restrict__ waT, unsigned short* __restrict__ ksT,
    unsigned short* __restrict__ pweT)
{
    int g = blockIdx.x * 256 + threadIdx.x;
    if (g < 49152) {
        int l = g >> 14, r = g & 16383, n = r >> 7, k = r & 127;
        wqT[g] = Wq[((l * 4 + (n >> 5)) * 128 + k) * 32 + (n & 31)];  // head-interleaved cols
    } else if (g < 98304) {
        int q = g - 49152; int l = q >> 14, r = q & 16383, n = r >> 7, k = r & 127;
        w1T[q] = W1[(l * 128 + k) * 128 + n];
    } else if (g < 147456) {
        int q = g - 98304; int l = q >> 14, r = q & 16383, n = r >> 7, k = r & 127;
        w2T[q] = W2[(l * 128 + k) * 128 + n];
    } else if (g < 155648) {
        int q = g - 147456; int n = q >> 7, k = q & 127;
        pw1T[q] = pw1[k * 64 + n];
    } else if (g < 204800) {
        int q = g - 155648; int l = q >> 14, r = q & 16383, n = r >> 7, k = r & 127;
        int hk = k >> 5, dk = k & 31;
        const float* kvp = kvs + (l * 4 + hk) * 1024 + dk * 32;
        const unsigned short* wop = Wo + (size_t)(l * 128 + hk * 32) * 128 + n;
        float s = 0.f;
        #pragma unroll 8
        for (int j = 0; j < 32; j++) s += kvp[j] * b2f(wop[j * 128]);
        waT[q] = f2b(s);
    } else if (g < 210944) {
        int q = g - 204800; int l = q >> 11, r = q & 2047, n = r >> 7, k = r & 127;
        unsigned short v = 0;
        if (n < 4 && (k >> 5) == n) v = f2b(kss[(l * 4 + n) * 32 + (k & 31)]);
        ksT[q] = v;
    } else if (g < 215040) {
        int q = g - 210944; int n = q >> 5, k = q & 31;   // pe_wT [128][32], k>=30 -> 0
        pweT[q] = (k < 30) ? pe_w[k * 128 + n] : (unsigned short)0;
    }
}

// ---------- the fused mega kernel: encode + 3 layers + projector ----------
// 128 rows/block, 4 waves; wave w owns rows [w*32, w*32+32) = 2 MFMA row-tiles.
// Weights read as B-fragments DIRECTLY FROM GLOBAL (L2-hot), no barriers in
// the layer loop. Dual-tc iteration: 4 independent MFMA accumulator chains
// per step (x0a/x1a/x0b/x1b) to fill the matrix pipe (round-8: 2 serial
// chains -> MfmaUtil 8%). Encode is itself an MFMA (K=32, padded feats).
// __launch_bounds__(256) with NO min-waves arg (the (256,2) cap caused the
// round-5/7 860 MB scratch spill).
#define LDA 136   // LDS row stride in ushorts (272B = 17*16B)

// dual-tc mm over a 128x128 [n][k] weight matrix; B-frags from global with
// pair prefetch. EPI sees: tc, x0 (rows r0c..+3), x1 (rows r0c+16..+19).
#define RUN_MM(AF, W, ...) do {                                               \
    const unsigned short* _base = (W) + l16 * 128 + qd * 8;                   \
    s8v _c[8]; s8v _n[8];                                                     \
    _Pragma("unroll")                                                         \
    for (int _k = 0; _k < 4; _k++) {                                          \
        _c[_k]     = *(const s8v*)(_base + _k * 32);                          \
        _c[4 + _k] = *(const s8v*)(_base + 2048 + _k * 32);                   \
    }                                                                         \
    _Pragma("unroll")                                                         \
    for (int _p = 0; _p < 4; _p++) {                                          \
        if (_p < 3) {                                                         \
            const unsigned short* _bp = _base + (_p * 2 + 2) * 2048;          \
            _Pragma("unroll")                                                 \
            for (int _k = 0; _k < 4; _k++) {                                  \
                _n[_k]     = *(const s8v*)(_bp + _k * 32);                    \
                _n[4 + _k] = *(const s8v*)(_bp + 2048 + _k * 32);             \
            }                                                                 \
        }                                                                     \
        f4v _x0a = {0.f,0.f,0.f,0.f}, _x1a = {0.f,0.f,0.f,0.f};               \
        f4v _x0b = {0.f,0.f,0.f,0.f}, _x1b = {0.f,0.f,0.f,0.f};               \
        _Pragma("unroll")                                                     \
        for (int _k = 0; _k < 4; _k++) {                                      \
            _x0a = MFMA_BF16(AF[0][_k], _c[_k],     _x0a, 0, 0, 0);           \
            _x1a = MFMA_BF16(AF[1][_k], _c[_k],     _x1a, 0, 0, 0);           \
            _x0b = MFMA_BF16(AF[0][_k], _c[4 + _k], _x0b, 0, 0, 0);           \
            _x1b = MFMA_BF16(AF[1][_k], _c[4 + _k], _x1b, 0, 0, 0);           \
        }                                                                     \
        { const int tc = _p * 2;     const f4v x0 = _x0a, x1 = _x1a; __VA_ARGS__ } \
        { const int tc = _p * 2 + 1; const f4v x0 = _x0b, x1 = _x1b; __VA_ARGS__ } \
        if (_p < 3) {                                                         \
            _Pragma("unroll")                                                 \
            for (int _k = 0; _k < 8; _k++) _c[_k] = _n[_k];                   \
        }                                                                     \
    }                                                                         \
} while (0)

// load A-fragments (2 row-tiles) for this wave's rows from sA
#define LOAD_AF(AF) do {                                                      \
    _Pragma("unroll")                                                         \
    for (int _t = 0; _t < 2; _t++)                                            \
        _Pragma("unroll")                                                     \
        for (int _k = 0; _k < 4; _k++)                                        \
            AF[_t][_k] = *(const s8v*)&sA[(rA0 + _t * 16) * LDA + _k * 32 + qd * 8]; \
} while (0)

__global__ __launch_bounds__(256) void mega_kernel(
    const unsigned short* __restrict__ qpts,
    const unsigned short* __restrict__ pweT,
    const unsigned short* __restrict__ pe_b,
    const unsigned short* __restrict__ wqT,
    const unsigned short* __restrict__ waT,
    const unsigned short* __restrict__ ksT,
    const unsigned short* __restrict__ w1T,
    const unsigned short* __restrict__ w2T,
    const unsigned short* __restrict__ bq,
    const unsigned short* __restrict__ bo,
    const unsigned short* __restrict__ b1,
    const unsigned short* __restrict__ b2,
    const unsigned short* __restrict__ pw1T,
    const unsigned short* __restrict__ pb1,
    const unsigned short* __restrict__ pw2,
    const unsigned short* __restrict__ pb2,
    void* __restrict__ outv, const int* __restrict__ flag)
{
    __shared__ __align__(16) unsigned short sA[128 * LDA];        // 34816 B
    __shared__ __align__(16) unsigned short sKsAll[3 * 16 * LDA]; // 13056 B
    __shared__ float biasAll[12 * 128];                           // 6144 B
    __shared__ float pebs[128];
    __shared__ float pb1s[64];
    __shared__ float w2s[192];
    __shared__ float pb2s[3];
    __shared__ float dens[128 * 4];                               // 2048 B

    int t = threadIdx.x;
    int wvi = t >> 6, ln = t & 63, qd = ln >> 4, l16 = ln & 15;
    int row0 = blockIdx.x * 128;
    int rA0 = wvi * 32 + l16;        // A-frag row, tile 0 (tile 1: +16)
    int r0c = wvi * 32 + qd * 4;     // C base row, tile 0 (tile 1: +16)

    // ===== one-time staging =====
    #pragma unroll
    for (int ll = 0; ll < 3; ll++)
        *(int4*)&sKsAll[(ll * 16 + (t >> 4)) * LDA + (t & 15) * 8] =
            ((const int4*)(ksT + ll * 2048))[t];
    for (int i = t; i < 1536; i += 256) {
        int l = i >> 9, rem = i & 511, which = rem >> 7, c = rem & 127;
        const unsigned short* bsrc = (which == 0) ? bq : (which == 1) ? bo
                                   : (which == 2) ? b1 : b2;
        biasAll[i] = b2f(bsrc[l * 128 + c]);
    }
    if (t < 128) pebs[t] = b2f(pe_b[t]);
    if (t < 64)  pb1s[t] = b2f(pb1[t]);
    if (t < 192) w2s[t] = b2f(pw2[t]);
    if (t < 3)   pb2s[t] = b2f(pb2[t]);
    __syncthreads();     // barrier #1 (the only one before the tail)

    float hres[2][4][8];   // fp32 residual, C-layout: [tile][i][tc]

    // ===== encode via MFMA: h = sin(feats @ pe_w + pe_b) =====
    // A: feats (k = qd*8+j, features 30/31 zero-padded); B: pe_wT [n][32]
    {
        unsigned pq0 = *(const unsigned*)(qpts + (size_t)(row0 + rA0) * 2);
        unsigned pq1 = *(const unsigned*)(qpts + (size_t)(row0 + rA0 + 16) * 2);
        s8v ae0, ae1;
        {
            float f8[8]; feats8(pq0, qd, f8);
            #pragma unroll
            for (int j = 0; j < 8; j++) ae0[j] = (short)f2b_rne(f8[j]);
        }
        {
            float f8[8]; feats8(pq1, qd, f8);
            #pragma unroll
            for (int j = 0; j < 8; j++) ae1[j] = (short)f2b_rne(f8[j]);
        }
        const unsigned short* pb = pweT + l16 * 32 + qd * 8;
        #pragma unroll
        for (int tc = 0; tc < 8; tc++) {
            s8v bfE = *(const s8v*)(pb + tc * 512);
            f4v x0 = {0.f, 0.f, 0.f, 0.f}, x1 = {0.f, 0.f, 0.f, 0.f};
            x0 = MFMA_BF16(ae0, bfE, x0, 0, 0, 0);
            x1 = MFMA_BF16(ae1, bfE, x1, 0, 0, 0);
            int c = tc * 16 + l16;
            float bb = pebs[c];
            #pragma unroll
            for (int i = 0; i < 4; i++) {
                float h0 = __sinf(x0[i] + bb);
                hres[0][i][tc] = h0;
                sA[(r0c + i) * LDA + c] = f2b_rne(h0);
                float h1 = __sinf(x1[i] + bb);
                hres[1][i][tc] = h1;
                sA[(r0c + 16 + i) * LDA + c] = f2b_rne(h1);
            }
        }
    }

    s8v af[2][4];

    // ===== 3 transformer layers (no barriers) =====
    for (int l = 0; l < 3; l++) {
        const float* bql = &biasAll[(l * 4 + 0) * 128];
        const float* bol = &biasAll[(l * 4 + 1) * 128];
        const float* b1l = &biasAll[(l * 4 + 2) * 128];
        const float* b2l = &biasAll[(l * 4 + 3) * 128];

        // mm1: qh = (h @ Wq + bq)^2 -> sA
        LOAD_AF(af);   // h
        RUN_MM(af, wqT + l * 16384, {
            int c = tc * 16 + l16;
            float bb = bql[c];
            _Pragma("unroll")
            for (int i = 0; i < 4; i++) {
                float v0 = x0[i] + bb;
                sA[(r0c + i) * LDA + c] = f2b_rne(v0 * v0);
                float v1 = x1[i] + bb;
                sA[(r0c + 16 + i) * LDA + c] = f2b_rne(v1 * v1);
            }
        });

        // den: dens[r][h] = qh_r . ksum_h   (B from LDS sKs)
        LOAD_AF(af);   // qh
        #pragma unroll
        for (int tile = 0; tile < 2; tile++) {
            f4v d = {0.f, 0.f, 0.f, 0.f};
            #pragma unroll
            for (int ks = 0; ks < 4; ks++) {
                s8v bf = *(const s8v*)&sKsAll[(l * 16 + l16) * LDA + ks * 32 + qd * 8];
                d = MFMA_BF16(af[tile][ks], bf, d, 0, 0, 0);
            }
            if (l16 < 4) {
                #pragma unroll
                for (int i = 0; i < 4; i++)
                    dens[(r0c + tile * 16 + i) * 4 + l16] = d[i];
            }
        }
        // scale qh fragments by z = 1/(den+1e-6); head of k-step ks == ks
        #pragma unroll
        for (int tile = 0; tile < 2; tile++) {
            int mr = rA0 + tile * 16;
            #pragma unroll
            for (int ks = 0; ks < 4; ks++) {
                float z = 1.f / (dens[mr * 4 + ks] + 1e-6f);
                #pragma unroll
                for (int j = 0; j < 8; j++) {
                    float q = b2f((unsigned short)af[tile][ks][j]);
                    af[tile][ks][j] = (short)f2b_rne(q * z);
                }
            }
        }

        // mm2: x = h + (z*qh) @ Wa + bo -> hres(fp32), sA(bf16)
        RUN_MM(af, waT + l * 16384, {
            int c = tc * 16 + l16;
            float bb = bol[c];
            _Pragma("unroll")
            for (int i = 0; i < 4; i++) {
                float v0 = hres[0][i][tc] + x0[i] + bb;
                hres[0][i][tc] = v0;
                sA[(r0c + i) * LDA + c] = f2b_rne(v0);
                float v1 = hres[1][i][tc] + x1[i] + bb;
                hres[1][i][tc] = v1;
                sA[(r0c + 16 + i) * LDA + c] = f2b_rne(v1);
            }
        });

        // mm3: t = gelu(x @ W1 + b1) -> sA
        LOAD_AF(af);   // x
        RUN_MM(af, w1T + l * 16384, {
            int c = tc * 16 + l16;
            float bb = b1l[c];
            _Pragma("unroll")
            for (int i = 0; i < 4; i++) {
                sA[(r0c + i) * LDA + c] = f2b_rne(gelu_t(x0[i] + bb));
                sA[(r0c + 16 + i) * LDA + c] = f2b_rne(gelu_t(x1[i] + bb));
            }
        });

        // mm4: h_new = x + t @ W2 + b2 -> hres, sA
        LOAD_AF(af);   // t
        RUN_MM(af, w2T + l * 16384, {
            int c = tc * 16 + l16;
            float bb = b2l[c];
            _Pragma("unroll")
            for (int i = 0; i < 4; i++) {
                float v0 = hres[0][i][tc] + x0[i] + bb;
                hres[0][i][tc] = v0;
                sA[(r0c + i) * LDA + c] = f2b_rne(v0);
                float v1 = hres[1][i][tc] + x1[i] + bb;
                hres[1][i][tc] = v1;
                sA[(r0c + 16 + i) * LDA + c] = f2b_rne(v1);
            }
        });
    }

    // ===== final projector: out = gelu(h @ pw1 + pb1) @ pw2 + pb2 =====
    {
        LOAD_AF(af);   // h final
        float* sAf = (float*)sA;   // [128][68] fp32 view (row = 272B = LDA)
        const unsigned short* base = pw1T + l16 * 128 + qd * 8;
        #pragma unroll
        for (int p = 0; p < 2; p++) {
            s8v cA[4], cB[4];
            #pragma unroll
            for (int ks = 0; ks < 4; ks++) {
                cA[ks] = *(const s8v*)(base + (p * 2) * 2048 + ks * 32);
                cB[ks] = *(const s8v*)(base + (p * 2 + 1) * 2048 + ks * 32);
            }
            f4v x0a = {0.f,0.f,0.f,0.f}, x1a = {0.f,0.f,0.f,0.f};
            f4v x0b = {0.f,0.f,0.f,0.f}, x1b = {0.f,0.f,0.f,0.f};
            #pragma unroll
            for (int ks = 0; ks < 4; ks++) {
                x0a = MFMA_BF16(af[0][ks], cA[ks], x0a, 0, 0, 0);
                x1a = MFMA_BF16(af[1][ks], cA[ks], x1a, 0, 0, 0);
                x0b = MFMA_BF16(af[0][ks], cB[ks], x0b, 0, 0, 0);
                x1b = MFMA_BF16(af[1][ks], cB[ks], x1b, 0, 0, 0);
            }
            int cAcol = (p * 2) * 16 + l16, cBcol = (p * 2 + 1) * 16 + l16;
            float bbA = pb1s[cAcol], bbB = pb1s[cBcol];
            #pragma unroll
            for (int i = 0; i < 4; i++) {
                sAf[(r0c + i) * 68 + cAcol] = gelu_t(x0a[i] + bbA);
                sAf[(r0c + 16 + i) * 68 + cAcol] = gelu_t(x1a[i] + bbA);
                sAf[(r0c + i) * 68 + cBcol] = gelu_t(x0b[i] + bbB);
                sAf[(r0c + 16 + i) * 68 + cBcol] = gelu_t(x1b[i] + bbB);
            }
        }
    }
    __syncthreads();   // barrier #2: cross-wave read below

    {
        const float* sAf = (const float*)sA;
        for (int idx = t; idx < 384; idx += 256) {
            int r = idx / 3, c = idx - r * 3;
            float s = pb2s[c];
            #pragma unroll 8
            for (int j = 0; j < 64; j++) s += sAf[r * 68 + j] * w2s[j * 3 + c];
            size_t o = (size_t)(row0 + r) * 3 + c;
            if (*flag) ((float*)outv)[o] = s;
            else       ((unsigned short*)outv)[o] = f2b(s);
        }
    }
}

// ---------- launch ----------
extern "C" void kernel_launch(void* const* d_in, const int* in_sizes, int n_in,
                              void* d_out, int out_size, void* d_ws, size_t ws_size,
                              hipStream_t stream) {
    const int N = in_sizes[0] / 2;   // 262144
    const int M = in_sizes[1] / 2;   // 4096

    ConvArgs ca;
    int total = 0;
    for (int i = 0; i < 22; i++) { ca.p[i] = d_in[i]; ca.off[i] = total; total += in_sizes[i]; }
    ca.off[22] = total;

    float* ws = (float*)d_ws;
    int* flag = (int*)ws;
    unsigned short* canon = (unsigned short*)(ws + 16);
    size_t canonF = ((size_t)(total + 1) / 2 + 15) & ~(size_t)15;
    float* b_enc = ws + 16 + canonF;                       // M*128
    float* khb   = b_enc + (size_t)M * 128;                // 12*M*32
    float* vhb   = khb + (size_t)12 * M * 32;              // 12*M*32
    float* kvs   = vhb + (size_t)12 * M * 32;              // 12288
    float* kss   = kvs + 12288;                            // 384
    unsigned short* wqT  = (unsigned short*)(kss + 384);   // 3*16384
    unsigned short* waT  = wqT + 49152;
    unsigned short* w1T  = waT + 49152;
    unsigned short* w2T  = w1T + 49152;
    unsigned short* ksT  = w2T + 49152;                    // 3*2048
    unsigned short* pw1T = ksT + 6144;                     // 8192
    unsigned short* pweT = pw1T + 8192;                    // 4096

    const unsigned short* c_qpts = canon + ca.off[0];
    const unsigned short* c_bpts = canon + ca.off[1];
    const unsigned short* c_pew  = canon + ca.off[2];
    const unsigned short* c_peb  = canon + ca.off[3];
    const unsigned short* c_bpew = canon + ca.off[4];
    const unsigned short* c_bpeb = canon + ca.off[5];
    const unsigned short* c_Wq   = canon + ca.off[6];
    const unsigned short* c_bq   = canon + ca.off[7];
    const unsigned short* c_Wk   = canon + ca.off[8];
    const unsigned short* c_bk   = canon + ca.off[9];
    const unsigned short* c_Wv   = canon + ca.off[10];
    const unsigned short* c_bv   = canon + ca.off[11];
    const unsigned short* c_Wo   = canon + ca.off[12];
    const unsigned short* c_bo   = canon + ca.off[13];
    const unsigned short* c_W1   = canon + ca.off[14];
    const unsigned short* c_b1   = canon + ca.off[15];
    const unsigned short* c_W2   = canon + ca.off[16];
    const unsigned short* c_b2   = canon + ca.off[17];
    const unsigned short* c_pw1  = canon + ca.off[18];
    const unsigned short* c_pb1  = canon + ca.off[19];
    const unsigned short* c_pw2  = canon + ca.off[20];
    const unsigned short* c_pb2  = canon + ca.off[21];

    convert_kernel<<<(total + 255) / 256, 256, 0, stream>>>(
        ca, (const unsigned short*)d_in[2], flag, canon, total);

    encode_kernel<<<M / 8, 256, 0, stream>>>(c_bpts, c_bpew, c_bpeb, b_enc);
    khvh_kernel<<<(12 * M * 32) / 256, 256, 0, stream>>>(
        b_enc, c_Wk, c_bk, c_Wv, c_bv, khb, vhb, kvs);
    kvred_kernel<<<96, 1024, 0, stream>>>(khb, vhb, kvs, kss);
    prep_kernel<<<215040 / 256, 256, 0, stream>>>(
        c_Wq, c_W1, c_W2, c_pw1, kvs, kss, c_Wo, c_pew,
        wqT, w1T, w2T, pw1T, waT, ksT, pweT);

    mega_kernel<<<N / 128, 256, 0, stream>>>(
        c_qpts, pweT, c_peb, wqT, waT, ksT, w1T, w2T,
        c_bq, c_bo, c_b1, c_b2, pw1T, c_pb1, c_pw2, c_pb2, d_out, flag);
}